// Round 2
// baseline (489.408 us; speedup 1.0000x reference)
//
#include <hip/hip_runtime.h>
#include <hip/hip_bf16.h>

// features [1024,1024] f32, W [1024,1024] f32 (nn.Linear: P = F @ W^T + b),
// b [1024] f32, prototypes [32768,1024] f32 (rows L2-normalized).
// Outputs: activations [1024,32768] f32, best_idx [1024] (float-coded ints).
//
// Strategy: projection via 3-way bf16 split MFMA (f32-floor accuracy) so the
// normalized projection matches the f32 reference direction to ~1e-7;
// similarity GEMM in plain bf16 MFMA (activation threshold tolerates it);
// argmax recovered EXACTLY by margin-screening the bf16 sims (worst-case
// bf16 GEMM error <= 2^-8) and recomputing candidates in f64.

typedef __attribute__((ext_vector_type(8))) short short8;   // 8 x bf16
typedef __attribute__((ext_vector_type(4))) float floatx4;  // MFMA C/D frag

__device__ __forceinline__ unsigned short f2bf(float f) {
  unsigned int u = __float_as_uint(f);
  u += 0x7fffu + ((u >> 16) & 1u);  // RNE
  return (unsigned short)(u >> 16);
}
__device__ __forceinline__ float bf2f(unsigned short h) {
  return __uint_as_float(((unsigned int)h) << 16);
}

// ---------------- f32 -> bf16 convert, 8 elems/thread (protos) -------------
__global__ __launch_bounds__(256) void cvt_f32_bf16(
    const float* __restrict__ src, unsigned short* __restrict__ dst, int n8) {
  int i = blockIdx.x * blockDim.x + threadIdx.x;
  if (i >= n8) return;
  const float4* s4 = (const float4*)src;
  float4 a = s4[2 * i];
  float4 b = s4[2 * i + 1];
  short8 o;
  o[0] = (short)f2bf(a.x); o[1] = (short)f2bf(a.y);
  o[2] = (short)f2bf(a.z); o[3] = (short)f2bf(a.w);
  o[4] = (short)f2bf(b.x); o[5] = (short)f2bf(b.y);
  o[6] = (short)f2bf(b.z); o[7] = (short)f2bf(b.w);
  ((short8*)dst)[i] = o;
}

// ---------------- f32 -> 3-way bf16 split (h + m + l ~= x to 2^-27) --------
__global__ __launch_bounds__(256) void cvt_split3(
    const float* __restrict__ src, unsigned short* __restrict__ H,
    unsigned short* __restrict__ Md, unsigned short* __restrict__ L, int n4) {
  int i = blockIdx.x * blockDim.x + threadIdx.x;
  if (i >= n4) return;
  float4 x = ((const float4*)src)[i];
  ushort4 h, m, l;
  float v, r;
  v = x.x; h.x = f2bf(v); r = v - bf2f(h.x); m.x = f2bf(r); l.x = f2bf(r - bf2f(m.x));
  v = x.y; h.y = f2bf(v); r = v - bf2f(h.y); m.y = f2bf(r); l.y = f2bf(r - bf2f(m.y));
  v = x.z; h.z = f2bf(v); r = v - bf2f(h.z); m.z = f2bf(r); l.z = f2bf(r - bf2f(m.z));
  v = x.w; h.w = f2bf(v); r = v - bf2f(h.w); m.w = f2bf(r); l.w = f2bf(r - bf2f(m.w));
  ((ushort4*)H)[i] = h; ((ushort4*)Md)[i] = m; ((ushort4*)L)[i] = l;
}

// ---------------- bf16 NT GEMM: C[M,N] = A[M,K] @ B[N,K]^T (m97 structure) --
__global__ __launch_bounds__(256) void gemm_nt_bf16(
    const unsigned short* __restrict__ A, const unsigned short* __restrict__ B,
    float* __restrict__ C, int M, int N, int K) {
  __shared__ unsigned short As[128 * 32];
  __shared__ unsigned short Bs[128 * 32];
  const int tid  = threadIdx.x;
  const int wave = tid >> 6;
  const int lane = tid & 63;
  const long tm = (long)blockIdx.y * 128;
  const long tn = (long)blockIdx.x * 128;
  const int wm = (wave & 1) * 64;
  const int wn = (wave >> 1) * 64;

  floatx4 acc[4][4];
#pragma unroll
  for (int i = 0; i < 4; i++)
#pragma unroll
    for (int j = 0; j < 4; j++) acc[i][j] = (floatx4){0.f, 0.f, 0.f, 0.f};

  const int rstage = tid >> 2;
  const int cstage = (tid & 3) * 8;
  const unsigned short* Abase = A + (tm + rstage) * (long)K + cstage;
  const unsigned short* Bbase = B + (tn + rstage) * (long)K + cstage;

  for (int k0 = 0; k0 < K; k0 += 32) {
    __builtin_amdgcn_global_load_lds(
        (const __attribute__((address_space(1))) void*)(Abase + k0),
        (__attribute__((address_space(3))) void*)(As + wave * 512), 16, 0, 0);
    __builtin_amdgcn_global_load_lds(
        (const __attribute__((address_space(1))) void*)(Abase + 64 * (long)K + k0),
        (__attribute__((address_space(3))) void*)(As + 2048 + wave * 512), 16, 0, 0);
    __builtin_amdgcn_global_load_lds(
        (const __attribute__((address_space(1))) void*)(Bbase + k0),
        (__attribute__((address_space(3))) void*)(Bs + wave * 512), 16, 0, 0);
    __builtin_amdgcn_global_load_lds(
        (const __attribute__((address_space(1))) void*)(Bbase + 64 * (long)K + k0),
        (__attribute__((address_space(3))) void*)(Bs + 2048 + wave * 512), 16, 0, 0);
    __syncthreads();

    short8 af[4], bfv[4];
    const int fr = lane & 15;
    const int koff = (lane >> 4) * 8;
#pragma unroll
    for (int mf = 0; mf < 4; mf++)
      af[mf] = *(const short8*)(As + (wm + mf * 16 + fr) * 32 + koff);
#pragma unroll
    for (int nf = 0; nf < 4; nf++)
      bfv[nf] = *(const short8*)(Bs + (wn + nf * 16 + fr) * 32 + koff);
#pragma unroll
    for (int mf = 0; mf < 4; mf++)
#pragma unroll
      for (int nf = 0; nf < 4; nf++)
        acc[mf][nf] = __builtin_amdgcn_mfma_f32_16x16x32_bf16(
            af[mf], bfv[nf], acc[mf][nf], 0, 0, 0);
    __syncthreads();
  }

  const long crow = tm + wm + ((lane >> 4) * 4);
  const long ccol = tn + wn + (lane & 15);
#pragma unroll
  for (int mf = 0; mf < 4; mf++)
#pragma unroll
    for (int nf = 0; nf < 4; nf++)
#pragma unroll
      for (int r = 0; r < 4; r++)
        C[(crow + mf * 16 + r) * (long)N + ccol + nf * 16] = acc[mf][nf][r];
}

// ---------------- split-bf16 NT GEMM (6 products): near-f32-exact ----------
// C = (Ah+Am+Al)(Bh+Bm+Bl)^T keeping hh | hm mh hl lh mm. 64x64 tile, BK=32.
__global__ __launch_bounds__(256) void gemm_split6_nt(
    const unsigned short* __restrict__ Ah, const unsigned short* __restrict__ Am,
    const unsigned short* __restrict__ Al, const unsigned short* __restrict__ Bh,
    const unsigned short* __restrict__ Bm, const unsigned short* __restrict__ Bl,
    float* __restrict__ C, int M, int N, int K) {
  __shared__ unsigned short sA[3][64 * 32];
  __shared__ unsigned short sB[3][64 * 32];
  const int tid  = threadIdx.x;
  const int wave = tid >> 6;
  const int lane = tid & 63;
  const long tm = (long)blockIdx.y * 64;
  const long tn = (long)blockIdx.x * 64;
  const int wm = (wave & 1) * 32;
  const int wn = (wave >> 1) * 32;

  floatx4 accH[2][2], accL[2][2];
#pragma unroll
  for (int i = 0; i < 2; i++)
#pragma unroll
    for (int j = 0; j < 2; j++) {
      accH[i][j] = (floatx4){0.f, 0.f, 0.f, 0.f};
      accL[i][j] = (floatx4){0.f, 0.f, 0.f, 0.f};
    }

  const int rstage = tid >> 2;
  const int cstage = (tid & 3) * 8;
  const long aoff = (tm + rstage) * (long)K + cstage;
  const long boff = (tn + rstage) * (long)K + cstage;
  const unsigned short* Asrc[3] = {Ah + aoff, Am + aoff, Al + aoff};
  const unsigned short* Bsrc[3] = {Bh + boff, Bm + boff, Bl + boff};

  for (int k0 = 0; k0 < K; k0 += 32) {
#pragma unroll
    for (int p = 0; p < 3; p++) {
      __builtin_amdgcn_global_load_lds(
          (const __attribute__((address_space(1))) void*)(Asrc[p] + k0),
          (__attribute__((address_space(3))) void*)(sA[p] + wave * 512), 16, 0, 0);
      __builtin_amdgcn_global_load_lds(
          (const __attribute__((address_space(1))) void*)(Bsrc[p] + k0),
          (__attribute__((address_space(3))) void*)(sB[p] + wave * 512), 16, 0, 0);
    }
    __syncthreads();

    const int fr = lane & 15;
    const int koff = (lane >> 4) * 8;
    short8 a_[3][2], b_[3][2];
#pragma unroll
    for (int p = 0; p < 3; p++)
#pragma unroll
      for (int mf = 0; mf < 2; mf++) {
        a_[p][mf] = *(const short8*)(sA[p] + (wm + mf * 16 + fr) * 32 + koff);
        b_[p][mf] = *(const short8*)(sB[p] + (wn + mf * 16 + fr) * 32 + koff);
      }
#pragma unroll
    for (int mf = 0; mf < 2; mf++)
#pragma unroll
      for (int nf = 0; nf < 2; nf++) {
        accH[mf][nf] = __builtin_amdgcn_mfma_f32_16x16x32_bf16(
            a_[0][mf], b_[0][nf], accH[mf][nf], 0, 0, 0);  // hh
        accL[mf][nf] = __builtin_amdgcn_mfma_f32_16x16x32_bf16(
            a_[0][mf], b_[1][nf], accL[mf][nf], 0, 0, 0);  // hm
        accL[mf][nf] = __builtin_amdgcn_mfma_f32_16x16x32_bf16(
            a_[1][mf], b_[0][nf], accL[mf][nf], 0, 0, 0);  // mh
        accL[mf][nf] = __builtin_amdgcn_mfma_f32_16x16x32_bf16(
            a_[0][mf], b_[2][nf], accL[mf][nf], 0, 0, 0);  // hl
        accL[mf][nf] = __builtin_amdgcn_mfma_f32_16x16x32_bf16(
            a_[2][mf], b_[0][nf], accL[mf][nf], 0, 0, 0);  // lh
        accL[mf][nf] = __builtin_amdgcn_mfma_f32_16x16x32_bf16(
            a_[1][mf], b_[1][nf], accL[mf][nf], 0, 0, 0);  // mm
      }
    __syncthreads();
  }

  const long crow = tm + wm + ((lane >> 4) * 4);
  const long ccol = tn + wn + (lane & 15);
#pragma unroll
  for (int mf = 0; mf < 2; mf++)
#pragma unroll
    for (int nf = 0; nf < 2; nf++)
#pragma unroll
      for (int r = 0; r < 4; r++)
        C[(crow + mf * 16 + r) * (long)N + ccol + nf * 16] =
            accH[mf][nf][r] + accL[mf][nf][r];
}

// ---------------- bias + L2-normalize rows -> bf16 Pn AND f32 Pn32 ---------
__global__ __launch_bounds__(256) void norm_bias_rows(
    const float* __restrict__ P, const float* __restrict__ bias,
    unsigned short* __restrict__ Pn, float* __restrict__ Pn32) {
  const int b = blockIdx.x, tid = threadIdx.x;
  float4 v = ((const float4*)(P + (long)b * 1024))[tid];
  float4 bb = ((const float4*)bias)[tid];
  v.x += bb.x; v.y += bb.y; v.z += bb.z; v.w += bb.w;
  float ss = v.x * v.x + v.y * v.y + v.z * v.z + v.w * v.w;
#pragma unroll
  for (int off = 32; off > 0; off >>= 1) ss += __shfl_down(ss, off);
  __shared__ float wred[4];
  if ((tid & 63) == 0) wred[tid >> 6] = ss;
  __syncthreads();
  float tot = wred[0] + wred[1] + wred[2] + wred[3];
  float inv = 1.0f / fmaxf(sqrtf(tot), 1e-12f);
  float4 p = make_float4(v.x * inv, v.y * inv, v.z * inv, v.w * inv);
  ((float4*)Pn32)[b * 256 + tid] = p;
  ushort4 o;
  o.x = f2bf(p.x); o.y = f2bf(p.y); o.z = f2bf(p.z); o.w = f2bf(p.w);
  ((ushort4*)Pn)[b * 256 + tid] = o;
}

// ------- softmax + activations + margin-screened EXACT argmax (f64) --------
__global__ __launch_bounds__(256) void softmax_argmax_refine(
    float* __restrict__ S, const float* __restrict__ Pn32,
    const float* __restrict__ protos, float* __restrict__ idx_out) {
  const int b = blockIdx.x, tid = threadIdx.x;
  const int wave = tid >> 6, lane = tid & 63;
  float* row = S + (long)b * 32768;

  float m = -3.4e38f, l = 0.f;
  for (int i = tid; i < 32768; i += 256) {
    float z = row[i] * 10.0f;
    if (z > m) { l = l * __expf(m - z) + 1.0f; m = z; }
    else l += __expf(z - m);
  }
#pragma unroll
  for (int off = 32; off > 0; off >>= 1) {
    float mo = __shfl_down(m, off);
    float lo = __shfl_down(l, off);
    float M = fmaxf(m, mo);
    l = l * __expf(m - M) + lo * __expf(mo - M);
    m = M;
  }
  __shared__ float sm_[4], sl_[4];
  __shared__ int cand[128];
  __shared__ int ncand;
  if (lane == 0) { sm_[wave] = m; sl_[wave] = l; }
  if (tid == 0) ncand = 0;
  __syncthreads();
  float M = fmaxf(fmaxf(sm_[0], sm_[1]), fmaxf(sm_[2], sm_[3]));
  float L = sl_[0] * __expf(sm_[0] - M) + sl_[1] * __expf(sm_[1] - M) +
            sl_[2] * __expf(sm_[2] - M) + sl_[3] * __expf(sm_[3] - M);
  float invL = 1.0f / L;
  // worst-case bf16 sim error <= 2^-8 * ||p||*||k|| = 0.0039; margin 0.012 > 2*Δ
  float thr = M * 0.1f - 0.012f;

  for (int i = tid; i < 32768; i += 256) {
    float s = row[i];
    row[i] = __expf(s * 10.0f - M) * invL;
    if (s >= thr) {
      int p = atomicAdd(&ncand, 1);
      if (p < 128) cand[p] = i;
    }
  }
  __syncthreads();
  int n = ncand < 128 ? ncand : 128;

  float4 pv = ((const float4*)(Pn32 + (long)b * 1024))[tid];
  __shared__ double dred[4];
  double best = -1e300;
  int besti = 0x7fffffff;
  for (int c = 0; c < n; c++) {
    int k = cand[c];
    float4 kv = ((const float4*)(protos + (long)k * 1024))[tid];
    double d = (double)pv.x * kv.x + (double)pv.y * kv.y +
               (double)pv.z * kv.z + (double)pv.w * kv.w;
#pragma unroll
    for (int off = 32; off > 0; off >>= 1) d += __shfl_down(d, off);
    if (lane == 0) dred[wave] = d;
    __syncthreads();
    if (tid == 0) {
      double tot = dred[0] + dred[1] + dred[2] + dred[3];
      if (tot > best || (tot == best && k < besti)) { best = tot; besti = k; }
    }
    __syncthreads();
  }
  if (tid == 0) idx_out[b] = (float)besti;
}

extern "C" void kernel_launch(void* const* d_in, const int* in_sizes, int n_in,
                              void* d_out, int out_size, void* d_ws, size_t ws_size,
                              hipStream_t stream) {
  const float* features = (const float*)d_in[0];
  const float* W        = (const float*)d_in[1];
  const float* bias     = (const float*)d_in[2];
  const float* protos   = (const float*)d_in[3];

  const size_t MB = 1024 * 1024;
  char* ws = (char*)d_ws;
  unsigned short* protoB = (unsigned short*)ws;              // 64 MiB
  unsigned short* Fh = (unsigned short*)(ws + 64 * MB);      // 2 MiB each
  unsigned short* Fm = (unsigned short*)(ws + 66 * MB);
  unsigned short* Fl = (unsigned short*)(ws + 68 * MB);
  unsigned short* Wh = (unsigned short*)(ws + 70 * MB);
  unsigned short* Wm = (unsigned short*)(ws + 72 * MB);
  unsigned short* Wl = (unsigned short*)(ws + 74 * MB);
  float*          P  = (float*)(ws + 76 * MB);               // 4 MiB
  // F/W splits dead after projection GEMM -> reuse their space:
  unsigned short* Pn   = (unsigned short*)(ws + 64 * MB);    // 2 MiB
  float*          Pn32 = (float*)(ws + 66 * MB);             // 4 MiB

  float* S = (float*)d_out;                      // [1024,32768]
  float* idx_out = S + (size_t)1024 * 32768;     // [1024] float-coded

  cvt_f32_bf16<<<16384, 256, 0, stream>>>(protos, protoB, 32768 * 1024 / 8);
  cvt_split3<<<1024, 256, 0, stream>>>(features, Fh, Fm, Fl, 1024 * 1024 / 4);
  cvt_split3<<<1024, 256, 0, stream>>>(W, Wh, Wm, Wl, 1024 * 1024 / 4);
  gemm_split6_nt<<<dim3(16, 16), 256, 0, stream>>>(Fh, Fm, Fl, Wh, Wm, Wl, P,
                                                   1024, 1024, 1024);
  norm_bias_rows<<<1024, 256, 0, stream>>>(P, bias, Pn, Pn32);
  gemm_nt_bf16<<<dim3(256, 8), 256, 0, stream>>>(Pn, protoB, S, 1024, 32768, 1024);
  softmax_argmax_refine<<<1024, 256, 0, stream>>>(S, Pn32, protos, idx_out);
}

// Round 3
// 442.363 us; speedup vs baseline: 1.1063x; 1.1063x over previous
//
#include <hip/hip_runtime.h>
#include <hip/hip_bf16.h>

// features [1024,1024] f32, W [1024,1024] f32 (nn.Linear: P = F @ W^T + b),
// b [1024] f32, prototypes [32768,1024] f32 (rows L2-normalized).
// Outputs: activations [1024,32768] f32, best_idx [1024] (float-coded ints).

typedef __attribute__((ext_vector_type(8))) short short8;   // 8 x bf16
typedef __attribute__((ext_vector_type(4))) float floatx4;  // MFMA C/D frag

__device__ __forceinline__ unsigned short f2bf(float f) {
  unsigned int u = __float_as_uint(f);
  u += 0x7fffu + ((u >> 16) & 1u);  // RNE
  return (unsigned short)(u >> 16);
}
__device__ __forceinline__ float bf2f(unsigned short h) {
  return __uint_as_float(((unsigned int)h) << 16);
}

// ---------------- f32 -> bf16 convert, 8 elems/thread (protos) -------------
__global__ __launch_bounds__(256) void cvt_f32_bf16(
    const float* __restrict__ src, unsigned short* __restrict__ dst, int n8) {
  int i = blockIdx.x * blockDim.x + threadIdx.x;
  if (i >= n8) return;
  const float4* s4 = (const float4*)src;
  float4 a = s4[2 * i];
  float4 b = s4[2 * i + 1];
  short8 o;
  o[0] = (short)f2bf(a.x); o[1] = (short)f2bf(a.y);
  o[2] = (short)f2bf(a.z); o[3] = (short)f2bf(a.w);
  o[4] = (short)f2bf(b.x); o[5] = (short)f2bf(b.y);
  o[6] = (short)f2bf(b.z); o[7] = (short)f2bf(b.w);
  ((short8*)dst)[i] = o;
}

// ---------------- f32 -> 3-way bf16 split (h + m + l ~= x to 2^-27) --------
__global__ __launch_bounds__(256) void cvt_split3(
    const float* __restrict__ src, unsigned short* __restrict__ H,
    unsigned short* __restrict__ Md, unsigned short* __restrict__ L, int n4) {
  int i = blockIdx.x * blockDim.x + threadIdx.x;
  if (i >= n4) return;
  float4 x = ((const float4*)src)[i];
  ushort4 h, m, l;
  float v, r;
  v = x.x; h.x = f2bf(v); r = v - bf2f(h.x); m.x = f2bf(r); l.x = f2bf(r - bf2f(m.x));
  v = x.y; h.y = f2bf(v); r = v - bf2f(h.y); m.y = f2bf(r); l.y = f2bf(r - bf2f(m.y));
  v = x.z; h.z = f2bf(v); r = v - bf2f(h.z); m.z = f2bf(r); l.z = f2bf(r - bf2f(m.z));
  v = x.w; h.w = f2bf(v); r = v - bf2f(h.w); m.w = f2bf(r); l.w = f2bf(r - bf2f(m.w));
  ((ushort4*)H)[i] = h; ((ushort4*)Md)[i] = m; ((ushort4*)L)[i] = l;
}

// ---------------- bf16 NT GEMM: C[M,N] = A[M,K] @ B[N,K]^T (m97 structure) --
__global__ __launch_bounds__(256) void gemm_nt_bf16(
    const unsigned short* __restrict__ A, const unsigned short* __restrict__ B,
    float* __restrict__ C, int M, int N, int K) {
  __shared__ unsigned short As[128 * 32];
  __shared__ unsigned short Bs[128 * 32];
  const int tid  = threadIdx.x;
  const int wave = tid >> 6;
  const int lane = tid & 63;
  const long tm = (long)blockIdx.y * 128;
  const long tn = (long)blockIdx.x * 128;
  const int wm = (wave & 1) * 64;
  const int wn = (wave >> 1) * 64;

  floatx4 acc[4][4];
#pragma unroll
  for (int i = 0; i < 4; i++)
#pragma unroll
    for (int j = 0; j < 4; j++) acc[i][j] = (floatx4){0.f, 0.f, 0.f, 0.f};

  const int rstage = tid >> 2;
  const int cstage = (tid & 3) * 8;
  const unsigned short* Abase = A + (tm + rstage) * (long)K + cstage;
  const unsigned short* Bbase = B + (tn + rstage) * (long)K + cstage;

  for (int k0 = 0; k0 < K; k0 += 32) {
    __builtin_amdgcn_global_load_lds(
        (const __attribute__((address_space(1))) void*)(Abase + k0),
        (__attribute__((address_space(3))) void*)(As + wave * 512), 16, 0, 0);
    __builtin_amdgcn_global_load_lds(
        (const __attribute__((address_space(1))) void*)(Abase + 64 * (long)K + k0),
        (__attribute__((address_space(3))) void*)(As + 2048 + wave * 512), 16, 0, 0);
    __builtin_amdgcn_global_load_lds(
        (const __attribute__((address_space(1))) void*)(Bbase + k0),
        (__attribute__((address_space(3))) void*)(Bs + wave * 512), 16, 0, 0);
    __builtin_amdgcn_global_load_lds(
        (const __attribute__((address_space(1))) void*)(Bbase + 64 * (long)K + k0),
        (__attribute__((address_space(3))) void*)(Bs + 2048 + wave * 512), 16, 0, 0);
    __syncthreads();

    short8 af[4], bfv[4];
    const int fr = lane & 15;
    const int koff = (lane >> 4) * 8;
#pragma unroll
    for (int mf = 0; mf < 4; mf++)
      af[mf] = *(const short8*)(As + (wm + mf * 16 + fr) * 32 + koff);
#pragma unroll
    for (int nf = 0; nf < 4; nf++)
      bfv[nf] = *(const short8*)(Bs + (wn + nf * 16 + fr) * 32 + koff);
#pragma unroll
    for (int mf = 0; mf < 4; mf++)
#pragma unroll
      for (int nf = 0; nf < 4; nf++)
        acc[mf][nf] = __builtin_amdgcn_mfma_f32_16x16x32_bf16(
            af[mf], bfv[nf], acc[mf][nf], 0, 0, 0);
    __syncthreads();
  }

  const long crow = tm + wm + ((lane >> 4) * 4);
  const long ccol = tn + wn + (lane & 15);
#pragma unroll
  for (int mf = 0; mf < 4; mf++)
#pragma unroll
    for (int nf = 0; nf < 4; nf++)
#pragma unroll
      for (int r = 0; r < 4; r++)
        C[(crow + mf * 16 + r) * (long)N + ccol + nf * 16] = acc[mf][nf][r];
}

// ---------------- split-bf16 NT GEMM (6 products), split-K partials --------
// Cpart[z] = partial over K-range [z*K/gz, (z+1)*K/gz). 64x64 tile, BK=32.
__global__ __launch_bounds__(256) void gemm_split6_nt(
    const unsigned short* __restrict__ Ah, const unsigned short* __restrict__ Am,
    const unsigned short* __restrict__ Al, const unsigned short* __restrict__ Bh,
    const unsigned short* __restrict__ Bm, const unsigned short* __restrict__ Bl,
    float* __restrict__ Cpart, int M, int N, int K) {
  __shared__ unsigned short sA[3][64 * 32];
  __shared__ unsigned short sB[3][64 * 32];
  const int tid  = threadIdx.x;
  const int wave = tid >> 6;
  const int lane = tid & 63;
  const long tm = (long)blockIdx.y * 64;
  const long tn = (long)blockIdx.x * 64;
  const int wm = (wave & 1) * 32;
  const int wn = (wave >> 1) * 32;
  const int ksize = K / gridDim.z;
  const int kbase = blockIdx.z * ksize;
  float* C = Cpart + (size_t)blockIdx.z * M * N;

  floatx4 accH[2][2], accL[2][2];
#pragma unroll
  for (int i = 0; i < 2; i++)
#pragma unroll
    for (int j = 0; j < 2; j++) {
      accH[i][j] = (floatx4){0.f, 0.f, 0.f, 0.f};
      accL[i][j] = (floatx4){0.f, 0.f, 0.f, 0.f};
    }

  const int rstage = tid >> 2;
  const int cstage = (tid & 3) * 8;
  const long aoff = (tm + rstage) * (long)K + cstage;
  const long boff = (tn + rstage) * (long)K + cstage;
  const unsigned short* Asrc[3] = {Ah + aoff, Am + aoff, Al + aoff};
  const unsigned short* Bsrc[3] = {Bh + boff, Bm + boff, Bl + boff};

  for (int k0 = kbase; k0 < kbase + ksize; k0 += 32) {
#pragma unroll
    for (int p = 0; p < 3; p++) {
      __builtin_amdgcn_global_load_lds(
          (const __attribute__((address_space(1))) void*)(Asrc[p] + k0),
          (__attribute__((address_space(3))) void*)(sA[p] + wave * 512), 16, 0, 0);
      __builtin_amdgcn_global_load_lds(
          (const __attribute__((address_space(1))) void*)(Bsrc[p] + k0),
          (__attribute__((address_space(3))) void*)(sB[p] + wave * 512), 16, 0, 0);
    }
    __syncthreads();

    const int fr = lane & 15;
    const int koff = (lane >> 4) * 8;
    short8 a_[3][2], b_[3][2];
#pragma unroll
    for (int p = 0; p < 3; p++)
#pragma unroll
      for (int mf = 0; mf < 2; mf++) {
        a_[p][mf] = *(const short8*)(sA[p] + (wm + mf * 16 + fr) * 32 + koff);
        b_[p][mf] = *(const short8*)(sB[p] + (wn + mf * 16 + fr) * 32 + koff);
      }
#pragma unroll
    for (int mf = 0; mf < 2; mf++)
#pragma unroll
      for (int nf = 0; nf < 2; nf++) {
        accH[mf][nf] = __builtin_amdgcn_mfma_f32_16x16x32_bf16(
            a_[0][mf], b_[0][nf], accH[mf][nf], 0, 0, 0);  // hh
        accL[mf][nf] = __builtin_amdgcn_mfma_f32_16x16x32_bf16(
            a_[0][mf], b_[1][nf], accL[mf][nf], 0, 0, 0);  // hm
        accL[mf][nf] = __builtin_amdgcn_mfma_f32_16x16x32_bf16(
            a_[1][mf], b_[0][nf], accL[mf][nf], 0, 0, 0);  // mh
        accL[mf][nf] = __builtin_amdgcn_mfma_f32_16x16x32_bf16(
            a_[0][mf], b_[2][nf], accL[mf][nf], 0, 0, 0);  // hl
        accL[mf][nf] = __builtin_amdgcn_mfma_f32_16x16x32_bf16(
            a_[2][mf], b_[0][nf], accL[mf][nf], 0, 0, 0);  // lh
        accL[mf][nf] = __builtin_amdgcn_mfma_f32_16x16x32_bf16(
            a_[1][mf], b_[1][nf], accL[mf][nf], 0, 0, 0);  // mm
      }
    __syncthreads();
  }

  const long crow = tm + wm + ((lane >> 4) * 4);
  const long ccol = tn + wn + (lane & 15);
#pragma unroll
  for (int mf = 0; mf < 2; mf++)
#pragma unroll
    for (int nf = 0; nf < 2; nf++)
#pragma unroll
      for (int r = 0; r < 4; r++)
        C[(crow + mf * 16 + r) * (long)N + ccol + nf * 16] =
            accH[mf][nf][r] + accL[mf][nf][r];
}

// ------- bias + reduce split-K partials + L2-normalize -> bf16 + f32 -------
__global__ __launch_bounds__(256) void norm_bias_rows(
    const float* __restrict__ P0, const float* __restrict__ P1, int nparts,
    const float* __restrict__ bias, unsigned short* __restrict__ Pn,
    float* __restrict__ Pn32) {
  const int b = blockIdx.x, tid = threadIdx.x;
  float4 v = ((const float4*)(P0 + (long)b * 1024))[tid];
  if (nparts == 2) {
    float4 v1 = ((const float4*)(P1 + (long)b * 1024))[tid];
    v.x += v1.x; v.y += v1.y; v.z += v1.z; v.w += v1.w;
  }
  float4 bb = ((const float4*)bias)[tid];
  v.x += bb.x; v.y += bb.y; v.z += bb.z; v.w += bb.w;
  float ss = v.x * v.x + v.y * v.y + v.z * v.z + v.w * v.w;
#pragma unroll
  for (int off = 32; off > 0; off >>= 1) ss += __shfl_down(ss, off);
  __shared__ float wred[4];
  if ((tid & 63) == 0) wred[tid >> 6] = ss;
  __syncthreads();
  float tot = wred[0] + wred[1] + wred[2] + wred[3];
  float inv = 1.0f / fmaxf(sqrtf(tot), 1e-12f);
  float4 p = make_float4(v.x * inv, v.y * inv, v.z * inv, v.w * inv);
  ((float4*)Pn32)[b * 256 + tid] = p;
  ushort4 o;
  o.x = f2bf(p.x); o.y = f2bf(p.y); o.z = f2bf(p.z); o.w = f2bf(p.w);
  ((ushort4*)Pn)[b * 256 + tid] = o;
}

// ------- softmax + activations + margin-screened EXACT argmax (f64) --------
// 2 passes, float4 everywhere. Pass1: branchless vectorized online max/sum
// (HBM read). Pass2: write activations + collect candidates (L3-hot read).
__global__ __launch_bounds__(256) void softmax_argmax_refine(
    float* __restrict__ S, const float* __restrict__ Pn32,
    const float* __restrict__ protos, float* __restrict__ idx_out) {
  const int b = blockIdx.x, tid = threadIdx.x;
  const int wave = tid >> 6, lane = tid & 63;
  float4* row4 = (float4*)(S + (long)b * 32768);

  float m = -3.4e38f, l = 0.f;
#pragma unroll 4
  for (int it = 0; it < 32; it++) {
    float4 v = row4[tid + 256 * it];
    float zx = v.x * 10.f, zy = v.y * 10.f, zz = v.z * 10.f, zw = v.w * 10.f;
    float m4 = fmaxf(fmaxf(zx, zy), fmaxf(zz, zw));
    float nm = fmaxf(m, m4);
    l = l * __expf(m - nm) + __expf(zx - nm) + __expf(zy - nm) +
        __expf(zz - nm) + __expf(zw - nm);
    m = nm;
  }
#pragma unroll
  for (int off = 1; off < 64; off <<= 1) {
    float mo = __shfl_xor(m, off);
    float lo = __shfl_xor(l, off);
    float nm = fmaxf(m, mo);
    l = l * __expf(m - nm) + lo * __expf(mo - nm);
    m = nm;
  }
  __shared__ float sm_[4], sl_[4];
  __shared__ int cand[64];
  __shared__ int ncand;
  if (lane == 0) { sm_[wave] = m; sl_[wave] = l; }
  if (tid == 0) ncand = 0;
  __syncthreads();
  float Mz = fmaxf(fmaxf(sm_[0], sm_[1]), fmaxf(sm_[2], sm_[3]));
  float L = sl_[0] * __expf(sm_[0] - Mz) + sl_[1] * __expf(sm_[1] - Mz) +
            sl_[2] * __expf(sm_[2] - Mz) + sl_[3] * __expf(sm_[3] - Mz);
  float invL = 1.0f / L;
  // worst-case bf16 GEMM sim error <= 2^-8 = 0.0039; margin 0.012 > 2*err
  float thr = Mz * 0.1f - 0.012f;  // sim-scale

#pragma unroll 4
  for (int it = 0; it < 32; it++) {
    int i4 = tid + 256 * it;
    float4 v = row4[i4];
    if (fmaxf(fmaxf(v.x, v.y), fmaxf(v.z, v.w)) >= thr) {
      if (v.x >= thr) { int p = atomicAdd(&ncand, 1); if (p < 64) cand[p] = i4 * 4; }
      if (v.y >= thr) { int p = atomicAdd(&ncand, 1); if (p < 64) cand[p] = i4 * 4 + 1; }
      if (v.z >= thr) { int p = atomicAdd(&ncand, 1); if (p < 64) cand[p] = i4 * 4 + 2; }
      if (v.w >= thr) { int p = atomicAdd(&ncand, 1); if (p < 64) cand[p] = i4 * 4 + 3; }
    }
    float4 e;
    e.x = __expf(v.x * 10.f - Mz) * invL;
    e.y = __expf(v.y * 10.f - Mz) * invL;
    e.z = __expf(v.z * 10.f - Mz) * invL;
    e.w = __expf(v.w * 10.f - Mz) * invL;
    row4[i4] = e;
  }
  __syncthreads();
  int n = ncand < 64 ? ncand : 64;

  float4 pv = ((const float4*)(Pn32 + (long)b * 1024))[tid];
  __shared__ double dred[4];
  double best = -1e300;
  int besti = 0x7fffffff;
  for (int c = 0; c < n; c++) {
    int k = cand[c];
    float4 kv = ((const float4*)(protos + (long)k * 1024))[tid];
    double d = (double)pv.x * kv.x + (double)pv.y * kv.y +
               (double)pv.z * kv.z + (double)pv.w * kv.w;
#pragma unroll
    for (int off = 32; off > 0; off >>= 1) d += __shfl_down(d, off);
    if (lane == 0) dred[wave] = d;
    __syncthreads();
    if (tid == 0) {
      double tot = dred[0] + dred[1] + dred[2] + dred[3];
      if (tot > best || (tot == best && k < besti)) { best = tot; besti = k; }
    }
    __syncthreads();
  }
  if (tid == 0) idx_out[b] = (float)besti;
}

extern "C" void kernel_launch(void* const* d_in, const int* in_sizes, int n_in,
                              void* d_out, int out_size, void* d_ws, size_t ws_size,
                              hipStream_t stream) {
  const float* features = (const float*)d_in[0];
  const float* W        = (const float*)d_in[1];
  const float* bias     = (const float*)d_in[2];
  const float* protos   = (const float*)d_in[3];

  const size_t MB = 1024 * 1024;
  char* ws = (char*)d_ws;
  unsigned short* protoB = (unsigned short*)ws;              // 64 MiB
  unsigned short* Fh = (unsigned short*)(ws + 64 * MB);      // 2 MiB each
  unsigned short* Fm = (unsigned short*)(ws + 66 * MB);
  unsigned short* Fl = (unsigned short*)(ws + 68 * MB);
  unsigned short* Wh = (unsigned short*)(ws + 70 * MB);
  unsigned short* Wm = (unsigned short*)(ws + 72 * MB);
  unsigned short* Wl = (unsigned short*)(ws + 74 * MB);
  float*          P0 = (float*)(ws + 76 * MB);               // 4 MiB
  float*          P1 = (float*)(ws + 80 * MB);               // 4 MiB (split-K)
  // F/W splits dead after projection GEMM -> reuse their space:
  unsigned short* Pn   = (unsigned short*)(ws + 64 * MB);    // 2 MiB
  float*          Pn32 = (float*)(ws + 66 * MB);             // 4 MiB

  // split-K=2 needs 84 MiB of ws; fall back to 1 otherwise (ws_size is
  // constant across calls -> same work every launch, graph-safe)
  const int ksplit = (ws_size >= 84 * MB) ? 2 : 1;

  float* S = (float*)d_out;                      // [1024,32768]
  float* idx_out = S + (size_t)1024 * 32768;     // [1024] float-coded

  cvt_f32_bf16<<<16384, 256, 0, stream>>>(protos, protoB, 32768 * 1024 / 8);
  cvt_split3<<<1024, 256, 0, stream>>>(features, Fh, Fm, Fl, 1024 * 1024 / 4);
  cvt_split3<<<1024, 256, 0, stream>>>(W, Wh, Wm, Wl, 1024 * 1024 / 4);
  gemm_split6_nt<<<dim3(16, 16, ksplit), 256, 0, stream>>>(
      Fh, Fm, Fl, Wh, Wm, Wl, P0, 1024, 1024, 1024);
  norm_bias_rows<<<1024, 256, 0, stream>>>(P0, P1, ksplit, bias, Pn, Pn32);
  gemm_nt_bf16<<<dim3(256, 8), 256, 0, stream>>>(Pn, protoB, S, 1024, 32768, 1024);
  softmax_argmax_refine<<<1024, 256, 0, stream>>>(S, Pn32, protos, idx_out);
}